// Round 7
// baseline (173.315 us; speedup 1.0000x reference)
//
#include <hip/hip_runtime.h>

#define THREADS 320          // 320 % 10 == 0 -> lane's column-block fixed
#define ROWS_PER_BLOCK 1024
#define F4_PER_BLOCK 10240   // ROWS_PER_BLOCK * 10
#define ITERS 32             // F4_PER_BLOCK / THREADS

typedef float f32x4 __attribute__((ext_vector_type(4)));

// Kernel A: S[i] = sin^2(theta/2) = 0.5 - 0.5*cos(theta) for all rows -> ws
__global__ __launch_bounds__(256) void sqm_prep(
    const float* __restrict__ x, float* __restrict__ Sg)
{
    const int i = (blockIdx.x * 256 + threadIdx.x) * 4;   // n = 2^20: exact
    const f32x4 v = *reinterpret_cast<const f32x4*>(x + i);
    f32x4 s;
    s.x = 0.5f - 0.5f * __cosf(v.x);
    s.y = 0.5f - 0.5f * __cosf(v.y);
    s.z = 0.5f - 0.5f * __cosf(v.z);
    s.w = 0.5f - 0.5f * __cosf(v.w);
    *reinterpret_cast<f32x4*>(Sg + i) = s;
}

// Kernel B: out[i][v] = Horner_S(P[4..0][v]) — pure load/FMA/store stream,
// no LDS, no barrier. Coefficients from L2-resident fcw, fixed per lane.
// q_weights drops out: |exp(-0.5j*real)|==1, so probs = state^2.
__global__ __launch_bounds__(THREADS) void sqm_main(
    const float* __restrict__ Sg,    // [n]
    const float* __restrict__ fcw,   // [40][4]
    const float* __restrict__ fcb,   // [40]
    float* __restrict__ out)         // [n][40]
{
    const int t = threadIdx.x;
    const int m = t % 10;            // fixed column-block (outputs 4m..4m+3)

    float P0[4], P1[4], P2[4], P3[4], P4[4];
    #pragma unroll
    for (int c = 0; c < 4; ++c) {
        const f32x4 w = *reinterpret_cast<const f32x4*>(&fcw[(4*m + c) * 4]);
        const float b = fcb[4*m + c];
        P0[c] = w.x + w.y + w.z + w.w + b;
        P1[c] = -2.f*w.x - 4.f*w.y - 6.f*w.z - 8.f*w.w;
        P2[c] =           4.f*w.y + 12.f*w.z + 24.f*w.w;
        P3[c] =                     -8.f*w.z - 32.f*w.w;
        P4[c] =                                16.f*w.w;
    }
    const f32x4 p0 = {P0[0], P0[1], P0[2], P0[3]};
    const f32x4 p1 = {P1[0], P1[1], P1[2], P1[3]};
    const f32x4 p2 = {P2[0], P2[1], P2[2], P2[3]};
    const f32x4 p3 = {P3[0], P3[1], P3[2], P3[3]};
    const f32x4 p4 = {P4[0], P4[1], P4[2], P4[3]};

    // Lane t, iter it covers f32x4 index t + it*320 -> row t/10 + it*32.
    const float* Sb = Sg + blockIdx.x * ROWS_PER_BLOCK + t / 10;
    f32x4* __restrict__ outp = reinterpret_cast<f32x4*>(out)
                             + (long long)blockIdx.x * F4_PER_BLOCK + t;
    #pragma unroll 8
    for (int it = 0; it < ITERS; ++it) {
        const float S = Sb[it * 32];        // coalesced + L1 broadcast
        f32x4 r = p4;
        r = r * S + p3;
        r = r * S + p2;
        r = r * S + p1;
        r = r * S + p0;
        outp[it * THREADS] = r;
    }
}

extern "C" void kernel_launch(void* const* d_in, const int* in_sizes, int n_in,
                              void* d_out, int out_size, void* d_ws, size_t ws_size,
                              hipStream_t stream) {
    const float* x   = (const float*)d_in[0];
    // d_in[1] = q_weights: unused — unit-magnitude phase cancels in |psi|^2
    const float* fcw = (const float*)d_in[2];
    const float* fcb = (const float*)d_in[3];
    float* out = (float*)d_out;
    float* Sg  = (float*)d_ws;             // 4 MB scratch (ws is far larger)
    const int n = in_sizes[0];             // 2^20

    hipLaunchKernelGGL(sqm_prep, dim3(n / 1024), dim3(256), 0, stream, x, Sg);
    hipLaunchKernelGGL(sqm_main, dim3(n / ROWS_PER_BLOCK), dim3(THREADS), 0,
                       stream, Sg, fcw, fcb, out);
}